// Round 1
// 404.449 us; speedup vs baseline: 2.4232x; 2.4232x over previous
//
#include <hip/hip_runtime.h>

#define N_TOK 32768
#define DIM   256
#define KCB   4096
#define MROWS 64           // rows per block
// ---- legacy-kernel tile params (fallback path) ----
#define KT    256
#define NKT   (KCB / KT)
#define DC    8
#define NDC   (DIM / DC)
#define ESD   258

// ws layout (bytes):
//   0      : double lossAcc (zeroed by 16B memset)
//   16     : float A[N_TOK]  -- numpy-replica fp32 ||x_i||^2
//   131088 : float C[KCB]    -- fp32 ||e_k||^2
//   147472 : ushort e16[KCB][DIM] -- bf16(e) for the approx MFMA pass (2 MB)
#define WS_A 16
#define WS_C (16 + 4 * N_TOK)
#define WS_E (WS_C + 4 * KCB)
#define WS_NEED_NEW ((size_t)WS_E + (size_t)2 * KCB * DIM)

#define CAP    28          // candidate list capacity per row
#define MARGIN 1.5e-3f     // > 2x worst-case bf16-approx error bound (~6.4e-4)

typedef __attribute__((ext_vector_type(8))) short short8v;  // 8 x bf16 bits
typedef __attribute__((ext_vector_type(4))) float f32x4;

__device__ __forceinline__ unsigned short f2bf_rne(float f) {
    unsigned u = __float_as_uint(f);
    unsigned r = (u + 0x7FFFu + ((u >> 16) & 1u)) >> 16;
    return (unsigned short)r;
}

// ---------------------------------------------------------------------------
// Kernel A: bit-exact replica of numpy's fp32 pairwise row sum-of-squares.
// UNCHANGED from the passing round.
__global__ __launch_bounds__(256) void xsq_np_kernel(const float* __restrict__ x,
                                                     float* __restrict__ A) {
#pragma clang fp contract(off)
    __shared__ float xr[4][256];
    const int tid = threadIdx.x;
    const int w = tid >> 6, l = tid & 63;
    const int row = blockIdx.x * 4 + w;
    float4 v = *(const float4*)(x + (size_t)row * DIM + l * 4);
    xr[w][l * 4 + 0] = v.x; xr[w][l * 4 + 1] = v.y;
    xr[w][l * 4 + 2] = v.z; xr[w][l * 4 + 3] = v.w;
    __syncthreads();
    const float* t = xr[w];
    const int g = (l >> 4) & 1;
    const int j = l & 15;
    const int base = g * 128 + j;
    float t0 = t[base +   0] * t[base +   0];
    float t1 = t[base +  16] * t[base +  16];
    float t2 = t[base +  32] * t[base +  32];
    float t3 = t[base +  48] * t[base +  48];
    float t4 = t[base +  64] * t[base +  64];
    float t5 = t[base +  80] * t[base +  80];
    float t6 = t[base +  96] * t[base +  96];
    float t7 = t[base + 112] * t[base + 112];
    float p = ((t0 + t1) + (t2 + t3)) + ((t4 + t5) + (t6 + t7));
    p = p + __shfl_xor(p, 8, 64);
    p = p + __shfl_xor(p, 4, 64);
    p = p + __shfl_xor(p, 2, 64);
    p = p + __shfl_xor(p, 1, 64);
    float other = __shfl(p, 16, 64);
    if (l == 0) A[row] = p + other;
}

// ---------------------------------------------------------------------------
// Kernel B: C[k] exact as before; additionally emits bf16(e) when e16 != null.
__global__ void esq_np_kernel(const float* __restrict__ emb, float* __restrict__ C,
                              unsigned short* __restrict__ e16) {
#pragma clang fp contract(off)
    int row  = blockIdx.x * 4 + (threadIdx.x >> 6);
    int lane = threadIdx.x & 63;
    float4 v = *(const float4*)(emb + (size_t)row * DIM + lane * 4);
    if (e16) {
        ushort4 h;
        h.x = f2bf_rne(v.x); h.y = f2bf_rne(v.y);
        h.z = f2bf_rne(v.z); h.w = f2bf_rne(v.w);
        *(ushort4*)(e16 + (size_t)row * DIM + lane * 4) = h;
    }
    float s0 = v.x * v.x, s1 = v.y * v.y, s2 = v.z * v.z, s3 = v.w * v.w;
    double q = (double)s0 + (double)s1 + (double)s2 + (double)s3;
    #pragma unroll
    for (int off = 32; off; off >>= 1) q += __shfl_xor(q, off, 64);
    if (lane == 0) C[row] = (float)q;
}

// ---------------------------------------------------------------------------
// Exact fp32 score, bit-identical arithmetic to the proven-passing kernel:
// sequential ascending-d fmaf chain; tmp = A - 2*dot; s = tmp + C.
__device__ __forceinline__ unsigned long long exact_pack(
    const float* __restrict__ emb, const float* __restrict__ C,
    const float* xsrow, float rowA, int k)
{
    const float4* er = (const float4*)(emb + (size_t)k * DIM);
    float acc = 0.f;
    #pragma unroll 8
    for (int d4 = 0; d4 < DIM / 4; ++d4) {
        float4 ev = er[d4];
        float4 xv = *(const float4*)(xsrow + d4 * 4);
        acc = fmaf(xv.x, ev.x, acc);
        acc = fmaf(xv.y, ev.y, acc);
        acc = fmaf(xv.z, ev.z, acc);
        acc = fmaf(xv.w, ev.w, acc);
    }
    float tmp = rowA - 2.0f * acc;
    float sc  = tmp + C[k];
    // scores are strictly positive (~||x-e||^2 ~ 200+): bit pattern is monotone
    return ((unsigned long long)__float_as_uint(sc) << 32) | (unsigned)k;
}

// ---------------------------------------------------------------------------
// Kernel C (new): bf16-MFMA approx sweep (min), sweep again (collect candidates
// within MARGIN), exact fp32 rescore of candidates, then epilogue.
__global__ __launch_bounds__(256, 2) void vq_mfma(
    const float* __restrict__ x, const float* __restrict__ emb,
    const unsigned short* __restrict__ e16,
    const float* __restrict__ A, const float* __restrict__ C,
    float* __restrict__ out, double* __restrict__ lossAcc)
{
    __shared__ float xs[MROWS][DIM];                              // 64 KiB
    __shared__ union {
        int cand[MROWS][CAP];                                     // 7 KiB
        unsigned long long best[4][MROWS];                        // (reused)
    } cb;
    __shared__ int    cnt[MROWS];
    __shared__ float  waveMin[4][MROWS];                          // also thr
    __shared__ int    sIdx[MROWS];
    __shared__ double sRed[4];

    const int tid = threadIdx.x;
    const int w   = tid >> 6;        // wave 0..3 (owns n-tiles i*4+w)
    const int l   = tid & 63;
    const int jj  = l & 15;          // MFMA row/col lane index
    const int g   = l >> 4;          // MFMA k-group / D row group
    const int rowBase = blockIdx.x * MROWS;

    // ---- stage x tile (fp32, exact) ----
    #pragma unroll
    for (int p = 0; p < 16; ++p) {
        int flat = p * 256 + tid;
        int row = flat >> 6, d = (flat & 63) * 4;
        *(float4*)&xs[row][d] = *(const float4*)(x + (size_t)(rowBase + row) * DIM + d);
    }
    if (tid < MROWS) cnt[tid] = 0;
    __syncthreads();

    // ---- build all A fragments in registers: 4 row-tiles x 8 k-steps ----
    // A[i][k]: i = jj, k-slot (g,e) -> d = 32*s + 8*g + e.  B uses the same
    // slot convention, so the contraction is correct for any internal k-perm.
    short8v Af[4][8];
    #pragma unroll
    for (int t = 0; t < 4; ++t)
        #pragma unroll
        for (int s = 0; s < 8; ++s) {
            const float* xp = &xs[t * 16 + jj][s * 32 + g * 8];
            float4 a = *(const float4*)xp;
            float4 b = *(const float4*)(xp + 4);
            short8v f;
            f[0] = (short)f2bf_rne(a.x); f[1] = (short)f2bf_rne(a.y);
            f[2] = (short)f2bf_rne(a.z); f[3] = (short)f2bf_rne(a.w);
            f[4] = (short)f2bf_rne(b.x); f[5] = (short)f2bf_rne(b.y);
            f[6] = (short)f2bf_rne(b.z); f[7] = (short)f2bf_rne(b.w);
            Af[t][s] = f;
        }

    const char* ebase = (const char*)e16;
    const int boff = jj * (DIM * 2) + g * 16;   // lane offset within e-tile

    float rmin[4][4];
    #pragma unroll
    for (int t = 0; t < 4; ++t)
        #pragma unroll
        for (int r = 0; r < 4; ++r) rmin[t][r] = 3.4e38f;
    float thr[4][4];

    for (int phase = 0; phase < 2; ++phase) {
        for (int i = 0; i < 64; ++i) {
            int nt = i * 4 + w;                       // 16-code tile index
            const short8v* bp =
                (const short8v*)(ebase + (size_t)nt * (16 * DIM * 2) + boff);
            short8v B[8];
            #pragma unroll
            for (int s = 0; s < 8; ++s) B[s] = bp[s * 4];   // +64B per k-step
            float Cv = C[nt * 16 + jj];
            f32x4 acc[4];
            #pragma unroll
            for (int t = 0; t < 4; ++t) acc[t] = (f32x4){0.f, 0.f, 0.f, 0.f};
            #pragma unroll
            for (int s = 0; s < 8; ++s) {
                #pragma unroll
                for (int t = 0; t < 4; ++t)
                    acc[t] = __builtin_amdgcn_mfma_f32_16x16x32_bf16(
                        Af[t][s], B[s], acc[t], 0, 0, 0);
            }
            if (phase == 0) {
                #pragma unroll
                for (int t = 0; t < 4; ++t)
                    #pragma unroll
                    for (int r = 0; r < 4; ++r) {
                        float sc = fmaf(-2.f, acc[t][r], Cv);
                        rmin[t][r] = fminf(rmin[t][r], sc);
                    }
            } else {
                #pragma unroll
                for (int t = 0; t < 4; ++t)
                    #pragma unroll
                    for (int r = 0; r < 4; ++r) {
                        float sc = fmaf(-2.f, acc[t][r], Cv);
                        if (sc <= thr[t][r]) {
                            int row = t * 16 + g * 4 + r;   // D: row=4g+r, col=jj
                            int p = atomicAdd(&cnt[row], 1);
                            if (p < CAP) cb.cand[row][p] = nt * 16 + jj;
                        }
                    }
            }
        }
        if (phase == 0) {
            // reduce per-(t,r) mins across the 16 code-lanes, then across waves
            #pragma unroll
            for (int t = 0; t < 4; ++t)
                #pragma unroll
                for (int r = 0; r < 4; ++r) {
                    float v = rmin[t][r];
                    #pragma unroll
                    for (int off = 1; off <= 8; off <<= 1)
                        v = fminf(v, __shfl_xor(v, off, 16));
                    rmin[t][r] = v;
                }
            if (jj == 0) {
                #pragma unroll
                for (int t = 0; t < 4; ++t)
                    #pragma unroll
                    for (int r = 0; r < 4; ++r)
                        waveMin[w][t * 16 + g * 4 + r] = rmin[t][r];
            }
            __syncthreads();
            if (tid < MROWS) {
                float m = fminf(fminf(waveMin[0][tid], waveMin[1][tid]),
                                fminf(waveMin[2][tid], waveMin[3][tid]));
                waveMin[0][tid] = m + MARGIN;          // threshold per row
            }
            __syncthreads();
            #pragma unroll
            for (int t = 0; t < 4; ++t)
                #pragma unroll
                for (int r = 0; r < 4; ++r)
                    thr[t][r] = waveMin[0][t * 16 + g * 4 + r];
        }
    }
    __syncthreads();

    // ---- exact fp32 rescore of candidates (4 threads per row) ----
    const int crow = tid & 63;
    const int sub  = tid >> 6;
    unsigned long long best = ~0ULL;
    {
        int cc = cnt[crow];
        float rowA = A[rowBase + crow];
        const float* xsrow = &xs[crow][0];
        if (cc <= CAP) {
            for (int c = sub; c < cc; c += 4) {
                unsigned long long pk = exact_pack(emb, C, xsrow, rowA, cb.cand[crow][c]);
                best = best < pk ? best : pk;
            }
        } else {
            // overflow fallback (prob ~0): full exact scan of this row
            for (int k = sub; k < KCB; k += 4) {
                unsigned long long pk = exact_pack(emb, C, xsrow, rowA, k);
                best = best < pk ? best : pk;
            }
        }
    }
    __syncthreads();                 // all cand reads done before union reuse
    cb.best[sub][crow] = best;
    __syncthreads();
    if (tid < MROWS) {
        unsigned long long b0 = cb.best[0][tid], b1 = cb.best[1][tid];
        unsigned long long b2 = cb.best[2][tid], b3 = cb.best[3][tid];
        unsigned long long b = b0 < b1 ? b0 : b1;
        unsigned long long c2 = b2 < b3 ? b2 : b3;
        b = b < c2 ? b : c2;
        int idx = (int)(unsigned)(b & 0xFFFFFFFFull);
        sIdx[tid] = idx;
        out[1 + (size_t)N_TOK * DIM + rowBase + tid] = (float)idx;
    }
    __syncthreads();

    // ---- outputs: quantized gather (exact) + fp64 loss partial (unchanged) ----
    double lsum = 0.0;
    for (int row = 0; row < MROWS; ++row) {
        int idx = sIdx[row];
        float q  = emb[(size_t)idx * DIM + tid];
        float xv = xs[row][tid];
        out[1 + (size_t)(rowBase + row) * DIM + tid] = q;
        double df = (double)q - (double)xv;
        lsum += df * df;
    }
    #pragma unroll
    for (int off = 1; off < 64; off <<= 1) lsum += __shfl_xor(lsum, off, 64);
    __syncthreads();
    if ((tid & 63) == 0) sRed[tid >> 6] = lsum;
    __syncthreads();
    if (tid == 0) atomicAdd(lossAcc, sRed[0] + sRed[1] + sRed[2] + sRed[3]);
}

// ---------------------------------------------------------------------------
// Legacy kernel (proven-passing), kept as fallback if ws is too small.
__global__ __launch_bounds__(256, 2) void vq_np(
    const float* __restrict__ x, const float* __restrict__ emb,
    const float* __restrict__ A, const float* __restrict__ C,
    float* __restrict__ out, double* __restrict__ lossAcc)
{
    __shared__ float xs[MROWS][DIM];
    __shared__ float est[DC][ESD];
    __shared__ float sA[MROWS];
    __shared__ int   sIdx[MROWS];
    __shared__ double sRed[4];

    const int tid = threadIdx.x;
    const int c = tid & 31;
    const int r = tid >> 5;
    const int rowBase = blockIdx.x * MROWS;

    if (tid < MROWS) sA[tid] = A[rowBase + tid];

    #pragma unroll
    for (int p = 0; p < 16; ++p) {
        int flat = p * 256 + tid;
        int row = flat >> 6, d = (flat & 63) * 4;
        float4 v = *(const float4*)(x + (size_t)(rowBase + row) * DIM + d);
        *(float4*)&xs[row][d] = v;
    }

    float m1[8];
    int   i1[8];
    #pragma unroll
    for (int ri = 0; ri < 8; ++ri) { m1[ri] = 3.4e38f; i1[ri] = 0; }

    for (int kt = 0; kt < NKT; ++kt) {
        float acc[8][8];
        #pragma unroll
        for (int ri = 0; ri < 8; ++ri)
            #pragma unroll
            for (int kk = 0; kk < 8; ++kk) acc[ri][kk] = 0.f;

        for (int dc = 0; dc < NDC; ++dc) {
            const float* src = emb + (size_t)(kt * KT + tid) * DIM + dc * DC;
            float4 ea = *(const float4*)(src);
            float4 eb = *(const float4*)(src + 4);
            __syncthreads();
            est[0][tid] = ea.x; est[1][tid] = ea.y; est[2][tid] = ea.z; est[3][tid] = ea.w;
            est[4][tid] = eb.x; est[5][tid] = eb.y; est[6][tid] = eb.z; est[7][tid] = eb.w;
            __syncthreads();
            #pragma unroll
            for (int d4 = 0; d4 < 2; ++d4) {
                float4 xf[8];
                #pragma unroll
                for (int ri = 0; ri < 8; ++ri)
                    xf[ri] = *(const float4*)&xs[r * 8 + ri][dc * DC + d4 * 4];
                #pragma unroll
                for (int dd = 0; dd < 4; ++dd) {
                    float2 ev[4];
                    #pragma unroll
                    for (int j = 0; j < 4; ++j)
                        ev[j] = *(const float2*)&est[d4 * 4 + dd][2 * c + 64 * j];
                    #pragma unroll
                    for (int ri = 0; ri < 8; ++ri) {
                        float xv = (dd == 0) ? xf[ri].x : (dd == 1) ? xf[ri].y
                                 : (dd == 2) ? xf[ri].z : xf[ri].w;
                        #pragma unroll
                        for (int j = 0; j < 4; ++j) {
                            acc[ri][2 * j]     = fmaf(xv, ev[j].x, acc[ri][2 * j]);
                            acc[ri][2 * j + 1] = fmaf(xv, ev[j].y, acc[ri][2 * j + 1]);
                        }
                    }
                }
            }
        }
        #pragma unroll
        for (int j = 0; j < 4; ++j) {
            float2 Cv = *(const float2*)&C[kt * KT + 2 * c + 64 * j];
            #pragma unroll
            for (int p = 0; p < 2; ++p) {
                int kg = kt * KT + 2 * c + 64 * j + p;
                float Ck = (p == 0) ? Cv.x : Cv.y;
                #pragma unroll
                for (int ri = 0; ri < 8; ++ri) {
                    float tmp = sA[r * 8 + ri] - 2.0f * acc[ri][2 * j + p];
                    float s   = tmp + Ck;
                    if (s < m1[ri]) { m1[ri] = s; i1[ri] = kg; }
                }
            }
        }
    }

    #pragma unroll
    for (int ri = 0; ri < 8; ++ri) {
        float a = m1[ri]; int ja = i1[ri];
        #pragma unroll
        for (int off = 1; off <= 16; off <<= 1) {
            float b  = __shfl_xor(a, off, 64);
            int   jb = __shfl_xor(ja, off, 64);
            if (b < a || (b == a && jb < ja)) { a = b; ja = jb; }
        }
        if (c == 0) sIdx[r * 8 + ri] = ja;
    }
    __syncthreads();

    if (tid < MROWS) {
        out[1 + (size_t)N_TOK * DIM + rowBase + tid] = (float)sIdx[tid];
    }
    double lsum = 0.0;
    for (int row = 0; row < MROWS; ++row) {
        int idx = sIdx[row];
        float q  = emb[(size_t)idx * DIM + tid];
        float xv = xs[row][tid];
        out[1 + (size_t)(rowBase + row) * DIM + tid] = q;
        double df = (double)q - (double)xv;
        lsum += df * df;
    }
    #pragma unroll
    for (int off = 1; off < 64; off <<= 1) lsum += __shfl_xor(lsum, off, 64);
    __syncthreads();
    if ((tid & 63) == 0) sRed[tid >> 6] = lsum;
    __syncthreads();
    if (tid == 0) {
        atomicAdd(lossAcc, sRed[0] + sRed[1] + sRed[2] + sRed[3]);
    }
}

// ---------------------------------------------------------------------------
__global__ void finalize_kernel(const double* __restrict__ lossAcc, float* __restrict__ out) {
    out[0] = (float)(0.5 * (*lossAcc) / (double)((size_t)N_TOK * DIM));
}

extern "C" void kernel_launch(void* const* d_in, const int* in_sizes, int n_in,
                              void* d_out, int out_size, void* d_ws, size_t ws_size,
                              hipStream_t stream) {
    const float* x   = (const float*)d_in[0];   // [16,2048,256] fp32
    const float* emb = (const float*)d_in[1];   // [4096,256] fp32
    float* out = (float*)d_out;

    double* lossAcc = (double*)d_ws;
    float*  A       = (float*)((char*)d_ws + WS_A);
    float*  C       = (float*)((char*)d_ws + WS_C);
    unsigned short* e16 = (unsigned short*)((char*)d_ws + WS_E);

    const bool use_new = ws_size >= WS_NEED_NEW;

    hipMemsetAsync(d_ws, 0, 16, stream);
    xsq_np_kernel<<<N_TOK / 4, 256, 0, stream>>>(x, A);
    esq_np_kernel<<<KCB / 4, 256, 0, stream>>>(emb, C, use_new ? e16 : nullptr);
    if (use_new)
        vq_mfma<<<N_TOK / MROWS, 256, 0, stream>>>(x, emb, e16, A, C, out, lossAcc);
    else
        vq_np<<<N_TOK / MROWS, 256, 0, stream>>>(x, emb, A, C, out, lossAcc);
    finalize_kernel<<<1, 1, 0, stream>>>(lossAcc, out);
}

// Round 2
// 369.236 us; speedup vs baseline: 2.6543x; 1.0954x over previous
//
#include <hip/hip_runtime.h>

#define N_TOK 32768
#define DIM   256
#define KCB   4096
#define MROWS 64           // rows per block
#define XSP   260          // padded xs row stride (floats): float4-aligned, de-conflicted
// ---- legacy-kernel tile params (fallback path) ----
#define KT    256
#define NKT   (KCB / KT)
#define DC    8
#define NDC   (DIM / DC)
#define ESD   258

// ws layout (bytes):
//   0      : double lossAcc (zeroed by 16B memset)
//   16     : float A[N_TOK]  -- numpy-replica fp32 ||x_i||^2
//   131088 : float C[KCB]    -- fp32 ||e_k||^2
//   147472 : ushort e16[KCB][DIM] -- bf16(e) for the approx MFMA pass (2 MB)
#define WS_A 16
#define WS_C (16 + 4 * N_TOK)
#define WS_E (WS_C + 4 * KCB)
#define WS_NEED_NEW ((size_t)WS_E + (size_t)2 * KCB * DIM)

#define CAP    28          // candidate list capacity per row
#define MARGIN 1.5e-3f     // > 2x worst-case bf16-approx error bound (~6.4e-4)

typedef __attribute__((ext_vector_type(8))) short short8v;  // 8 x bf16 bits
typedef __attribute__((ext_vector_type(4))) float f32x4;

__device__ __forceinline__ unsigned short f2bf_rne(float f) {
    unsigned u = __float_as_uint(f);
    unsigned r = (u + 0x7FFFu + ((u >> 16) & 1u)) >> 16;
    return (unsigned short)r;
}

// ---------------------------------------------------------------------------
// Kernel A: bit-exact replica of numpy's fp32 pairwise row sum-of-squares.
__global__ __launch_bounds__(256) void xsq_np_kernel(const float* __restrict__ x,
                                                     float* __restrict__ A) {
#pragma clang fp contract(off)
    __shared__ float xr[4][256];
    const int tid = threadIdx.x;
    const int w = tid >> 6, l = tid & 63;
    const int row = blockIdx.x * 4 + w;
    float4 v = *(const float4*)(x + (size_t)row * DIM + l * 4);
    xr[w][l * 4 + 0] = v.x; xr[w][l * 4 + 1] = v.y;
    xr[w][l * 4 + 2] = v.z; xr[w][l * 4 + 3] = v.w;
    __syncthreads();
    const float* t = xr[w];
    const int g = (l >> 4) & 1;
    const int j = l & 15;
    const int base = g * 128 + j;
    float t0 = t[base +   0] * t[base +   0];
    float t1 = t[base +  16] * t[base +  16];
    float t2 = t[base +  32] * t[base +  32];
    float t3 = t[base +  48] * t[base +  48];
    float t4 = t[base +  64] * t[base +  64];
    float t5 = t[base +  80] * t[base +  80];
    float t6 = t[base +  96] * t[base +  96];
    float t7 = t[base + 112] * t[base + 112];
    float p = ((t0 + t1) + (t2 + t3)) + ((t4 + t5) + (t6 + t7));
    p = p + __shfl_xor(p, 8, 64);
    p = p + __shfl_xor(p, 4, 64);
    p = p + __shfl_xor(p, 2, 64);
    p = p + __shfl_xor(p, 1, 64);
    float other = __shfl(p, 16, 64);
    if (l == 0) A[row] = p + other;
}

// ---------------------------------------------------------------------------
// Kernel B: C[k] exact; also emits bf16(e) when e16 != null.
__global__ void esq_np_kernel(const float* __restrict__ emb, float* __restrict__ C,
                              unsigned short* __restrict__ e16) {
#pragma clang fp contract(off)
    int row  = blockIdx.x * 4 + (threadIdx.x >> 6);
    int lane = threadIdx.x & 63;
    float4 v = *(const float4*)(emb + (size_t)row * DIM + lane * 4);
    if (e16) {
        ushort4 h;
        h.x = f2bf_rne(v.x); h.y = f2bf_rne(v.y);
        h.z = f2bf_rne(v.z); h.w = f2bf_rne(v.w);
        *(ushort4*)(e16 + (size_t)row * DIM + lane * 4) = h;
    }
    float s0 = v.x * v.x, s1 = v.y * v.y, s2 = v.z * v.z, s3 = v.w * v.w;
    double q = (double)s0 + (double)s1 + (double)s2 + (double)s3;
    #pragma unroll
    for (int off = 32; off; off >>= 1) q += __shfl_xor(q, off, 64);
    if (lane == 0) C[row] = (float)q;
}

// ---------------------------------------------------------------------------
// Exact fp32 score, bit-identical arithmetic to the proven-passing kernel.
__device__ __forceinline__ unsigned long long exact_pack(
    const float* __restrict__ emb, const float* __restrict__ C,
    const float* xsrow, float rowA, int k)
{
    const float4* er = (const float4*)(emb + (size_t)k * DIM);
    float acc = 0.f;
    #pragma unroll 8
    for (int d4 = 0; d4 < DIM / 4; ++d4) {
        float4 ev = er[d4];
        float4 xv = *(const float4*)(xsrow + d4 * 4);
        acc = fmaf(xv.x, ev.x, acc);
        acc = fmaf(xv.y, ev.y, acc);
        acc = fmaf(xv.z, ev.z, acc);
        acc = fmaf(xv.w, ev.w, acc);
    }
    float tmp = rowA - 2.0f * acc;
    float sc  = tmp + C[k];
    // scores strictly positive: bit pattern is monotone
    return ((unsigned long long)__float_as_uint(sc) << 32) | (unsigned)k;
}

// ---------------------------------------------------------------------------
// Kernel C: bf16-MFMA approx sweep with double-buffered B prefetch, exact
// fp32 rescore of margin candidates, then epilogue.
__global__ __launch_bounds__(256, 2) void vq_mfma(
    const float* __restrict__ x, const float* __restrict__ emb,
    const unsigned short* __restrict__ e16,
    const float* __restrict__ A, const float* __restrict__ C,
    float* __restrict__ out, double* __restrict__ lossAcc)
{
    __shared__ float xs[MROWS][XSP];                              // 65 KiB padded
    __shared__ union {
        int cand[MROWS][CAP];
        unsigned long long best[4][MROWS];
    } cb;
    __shared__ int    cnt[MROWS];
    __shared__ float  waveMin[4][MROWS];
    __shared__ int    sIdx[MROWS];
    __shared__ double sRed[4];

    const int tid = threadIdx.x;
    const int w   = tid >> 6;        // wave 0..3 (owns n-tiles i*4+w)
    const int l   = tid & 63;
    const int jj  = l & 15;          // MFMA row/col lane index
    const int g   = l >> 4;          // MFMA k-group / D row group
    const int rowBase = blockIdx.x * MROWS;

    // ---- stage x tile (fp32, exact) ----
    #pragma unroll
    for (int p = 0; p < 16; ++p) {
        int flat = p * 256 + tid;
        int row = flat >> 6, d = (flat & 63) * 4;
        *(float4*)&xs[row][d] = *(const float4*)(x + (size_t)(rowBase + row) * DIM + d);
    }
    if (tid < MROWS) cnt[tid] = 0;
    __syncthreads();

    // ---- build all A fragments in registers: 4 row-tiles x 8 k-steps ----
    // Same k-slot convention for A and B -> contraction correct under any
    // internal k permutation. xs rows padded to XSP: frag-build reads now hit
    // rotating banks (was 16-way conflict at stride 256).
    short8v Af[4][8];
    #pragma unroll
    for (int t = 0; t < 4; ++t)
        #pragma unroll
        for (int s = 0; s < 8; ++s) {
            const float* xp = &xs[t * 16 + jj][s * 32 + g * 8];
            float4 a = *(const float4*)xp;
            float4 b = *(const float4*)(xp + 4);
            short8v f;
            f[0] = (short)f2bf_rne(a.x); f[1] = (short)f2bf_rne(a.y);
            f[2] = (short)f2bf_rne(a.z); f[3] = (short)f2bf_rne(a.w);
            f[4] = (short)f2bf_rne(b.x); f[5] = (short)f2bf_rne(b.y);
            f[6] = (short)f2bf_rne(b.z); f[7] = (short)f2bf_rne(b.w);
            Af[t][s] = f;
        }

    // per-lane base into e16 (tile stride 16*DIM*2 = 8192 B)
    const char* ebase = (const char*)e16 + jj * (DIM * 2) + g * 16;

    // phase 0: running min; after phase-0 reduction: per-row threshold.
    float mth[4][4];
    #pragma unroll
    for (int t = 0; t < 4; ++t)
        #pragma unroll
        for (int r = 0; r < 4; ++r) mth[t][r] = 3.4e38f;

    #pragma unroll
    for (int phase = 0; phase < 2; ++phase) {
        short8v BA[8], BB[8];
        float   CA, CB;

        // preload tile i=0 (nt = w)
        {
            const short8v* bp = (const short8v*)(ebase + (size_t)w * 8192);
            #pragma unroll
            for (int s = 0; s < 8; ++s) BA[s] = bp[s * 4];
            CA = C[w * 16 + jj];
        }

        // process(B, Cv, ti): 32 MFMA + score handling for tile ti*4+w
        auto process = [&](const short8v (&B)[8], float Cv, int ti) {
            f32x4 acc[4];
            #pragma unroll
            for (int t = 0; t < 4; ++t) acc[t] = (f32x4){0.f, 0.f, 0.f, 0.f};
            __builtin_amdgcn_s_setprio(1);
            #pragma unroll
            for (int s = 0; s < 8; ++s) {
                #pragma unroll
                for (int t = 0; t < 4; ++t)
                    acc[t] = __builtin_amdgcn_mfma_f32_16x16x32_bf16(
                        Af[t][s], B[s], acc[t], 0, 0, 0);
            }
            __builtin_amdgcn_s_setprio(0);
            if (phase == 0) {
                #pragma unroll
                for (int t = 0; t < 4; ++t)
                    #pragma unroll
                    for (int r = 0; r < 4; ++r) {
                        float sc = fmaf(-2.f, acc[t][r], Cv);
                        mth[t][r] = fminf(mth[t][r], sc);
                    }
            } else {
                int kc = (ti * 4 + w) * 16 + jj;
                #pragma unroll
                for (int t = 0; t < 4; ++t)
                    #pragma unroll
                    for (int r = 0; r < 4; ++r) {
                        float sc = fmaf(-2.f, acc[t][r], Cv);
                        if (sc <= mth[t][r]) {
                            int row = t * 16 + g * 4 + r;   // D: row=4g+r, col=jj
                            int p = atomicAdd(&cnt[row], 1);
                            if (p < CAP) cb.cand[row][p] = kc;
                        }
                    }
            }
        };

        #pragma unroll 1
        for (int i = 0; i < 64; i += 2) {
            {   // prefetch tile i+1 -> BB (lands after BA's MFMAs)
                int nt = (i + 1) * 4 + w;
                const short8v* bp = (const short8v*)(ebase + (size_t)nt * 8192);
                #pragma unroll
                for (int s = 0; s < 8; ++s) BB[s] = bp[s * 4];
                CB = C[nt * 16 + jj];
            }
            process(BA, CA, i);
            {   // prefetch tile i+2 -> BA (wraps harmlessly at the end)
                int nt = ((i + 2) & 63) * 4 + w;
                const short8v* bp = (const short8v*)(ebase + (size_t)nt * 8192);
                #pragma unroll
                for (int s = 0; s < 8; ++s) BA[s] = bp[s * 4];
                CA = C[nt * 16 + jj];
            }
            process(BB, CB, i + 1);
        }

        if (phase == 0) {
            // reduce per-(t,r) mins across the 16 code-lanes, then across waves
            #pragma unroll
            for (int t = 0; t < 4; ++t)
                #pragma unroll
                for (int r = 0; r < 4; ++r) {
                    float v = mth[t][r];
                    #pragma unroll
                    for (int off = 1; off <= 8; off <<= 1)
                        v = fminf(v, __shfl_xor(v, off, 16));
                    mth[t][r] = v;
                }
            if (jj == 0) {
                #pragma unroll
                for (int t = 0; t < 4; ++t)
                    #pragma unroll
                    for (int r = 0; r < 4; ++r)
                        waveMin[w][t * 16 + g * 4 + r] = mth[t][r];
            }
            __syncthreads();
            if (tid < MROWS) {
                float m = fminf(fminf(waveMin[0][tid], waveMin[1][tid]),
                                fminf(waveMin[2][tid], waveMin[3][tid]));
                waveMin[0][tid] = m + MARGIN;          // threshold per row
            }
            __syncthreads();
            #pragma unroll
            for (int t = 0; t < 4; ++t)
                #pragma unroll
                for (int r = 0; r < 4; ++r)
                    mth[t][r] = waveMin[0][t * 16 + g * 4 + r];
        }
    }
    __syncthreads();

    // ---- exact fp32 rescore of candidates (4 threads per row) ----
    const int crow = tid & 63;
    const int sub  = tid >> 6;
    unsigned long long best = ~0ULL;
    {
        int cc = cnt[crow];
        float rowA = A[rowBase + crow];
        const float* xsrow = &xs[crow][0];
        if (cc <= CAP) {
            for (int c = sub; c < cc; c += 4) {
                unsigned long long pk = exact_pack(emb, C, xsrow, rowA, cb.cand[crow][c]);
                best = best < pk ? best : pk;
            }
        } else {
            // overflow fallback (prob ~0): full exact scan of this row
            for (int k = sub; k < KCB; k += 4) {
                unsigned long long pk = exact_pack(emb, C, xsrow, rowA, k);
                best = best < pk ? best : pk;
            }
        }
    }
    __syncthreads();                 // all cand reads done before union reuse
    cb.best[sub][crow] = best;
    __syncthreads();
    if (tid < MROWS) {
        unsigned long long b0 = cb.best[0][tid], b1 = cb.best[1][tid];
        unsigned long long b2 = cb.best[2][tid], b3 = cb.best[3][tid];
        unsigned long long b = b0 < b1 ? b0 : b1;
        unsigned long long c2 = b2 < b3 ? b2 : b3;
        b = b < c2 ? b : c2;
        int idx = (int)(unsigned)(b & 0xFFFFFFFFull);
        sIdx[tid] = idx;
        out[1 + (size_t)N_TOK * DIM + rowBase + tid] = (float)idx;
    }
    __syncthreads();

    // ---- outputs: quantized gather (exact) + fp64 loss partial ----
    double lsum = 0.0;
    for (int row = 0; row < MROWS; ++row) {
        int idx = sIdx[row];
        float q  = emb[(size_t)idx * DIM + tid];
        float xv = xs[row][tid];
        out[1 + (size_t)(rowBase + row) * DIM + tid] = q;
        double df = (double)q - (double)xv;
        lsum += df * df;
    }
    #pragma unroll
    for (int off = 1; off < 64; off <<= 1) lsum += __shfl_xor(lsum, off, 64);
    __syncthreads();
    if ((tid & 63) == 0) sRed[tid >> 6] = lsum;
    __syncthreads();
    if (tid == 0) atomicAdd(lossAcc, sRed[0] + sRed[1] + sRed[2] + sRed[3]);
}

// ---------------------------------------------------------------------------
// Legacy kernel (proven-passing), fallback if ws is too small.
__global__ __launch_bounds__(256, 2) void vq_np(
    const float* __restrict__ x, const float* __restrict__ emb,
    const float* __restrict__ A, const float* __restrict__ C,
    float* __restrict__ out, double* __restrict__ lossAcc)
{
    __shared__ float xs[MROWS][DIM];
    __shared__ float est[DC][ESD];
    __shared__ float sA[MROWS];
    __shared__ int   sIdx[MROWS];
    __shared__ double sRed[4];

    const int tid = threadIdx.x;
    const int c = tid & 31;
    const int r = tid >> 5;
    const int rowBase = blockIdx.x * MROWS;

    if (tid < MROWS) sA[tid] = A[rowBase + tid];

    #pragma unroll
    for (int p = 0; p < 16; ++p) {
        int flat = p * 256 + tid;
        int row = flat >> 6, d = (flat & 63) * 4;
        float4 v = *(const float4*)(x + (size_t)(rowBase + row) * DIM + d);
        *(float4*)&xs[row][d] = v;
    }

    float m1[8];
    int   i1[8];
    #pragma unroll
    for (int ri = 0; ri < 8; ++ri) { m1[ri] = 3.4e38f; i1[ri] = 0; }

    for (int kt = 0; kt < NKT; ++kt) {
        float acc[8][8];
        #pragma unroll
        for (int ri = 0; ri < 8; ++ri)
            #pragma unroll
            for (int kk = 0; kk < 8; ++kk) acc[ri][kk] = 0.f;

        for (int dc = 0; dc < NDC; ++dc) {
            const float* src = emb + (size_t)(kt * KT + tid) * DIM + dc * DC;
            float4 ea = *(const float4*)(src);
            float4 eb = *(const float4*)(src + 4);
            __syncthreads();
            est[0][tid] = ea.x; est[1][tid] = ea.y; est[2][tid] = ea.z; est[3][tid] = ea.w;
            est[4][tid] = eb.x; est[5][tid] = eb.y; est[6][tid] = eb.z; est[7][tid] = eb.w;
            __syncthreads();
            #pragma unroll
            for (int d4 = 0; d4 < 2; ++d4) {
                float4 xf[8];
                #pragma unroll
                for (int ri = 0; ri < 8; ++ri)
                    xf[ri] = *(const float4*)&xs[r * 8 + ri][dc * DC + d4 * 4];
                #pragma unroll
                for (int dd = 0; dd < 4; ++dd) {
                    float2 ev[4];
                    #pragma unroll
                    for (int j = 0; j < 4; ++j)
                        ev[j] = *(const float2*)&est[d4 * 4 + dd][2 * c + 64 * j];
                    #pragma unroll
                    for (int ri = 0; ri < 8; ++ri) {
                        float xv = (dd == 0) ? xf[ri].x : (dd == 1) ? xf[ri].y
                                 : (dd == 2) ? xf[ri].z : xf[ri].w;
                        #pragma unroll
                        for (int j = 0; j < 4; ++j) {
                            acc[ri][2 * j]     = fmaf(xv, ev[j].x, acc[ri][2 * j]);
                            acc[ri][2 * j + 1] = fmaf(xv, ev[j].y, acc[ri][2 * j + 1]);
                        }
                    }
                }
            }
        }
        #pragma unroll
        for (int j = 0; j < 4; ++j) {
            float2 Cv = *(const float2*)&C[kt * KT + 2 * c + 64 * j];
            #pragma unroll
            for (int p = 0; p < 2; ++p) {
                int kg = kt * KT + 2 * c + 64 * j + p;
                float Ck = (p == 0) ? Cv.x : Cv.y;
                #pragma unroll
                for (int ri = 0; ri < 8; ++ri) {
                    float tmp = sA[r * 8 + ri] - 2.0f * acc[ri][2 * j + p];
                    float s   = tmp + Ck;
                    if (s < m1[ri]) { m1[ri] = s; i1[ri] = kg; }
                }
            }
        }
    }

    #pragma unroll
    for (int ri = 0; ri < 8; ++ri) {
        float a = m1[ri]; int ja = i1[ri];
        #pragma unroll
        for (int off = 1; off <= 16; off <<= 1) {
            float b  = __shfl_xor(a, off, 64);
            int   jb = __shfl_xor(ja, off, 64);
            if (b < a || (b == a && jb < ja)) { a = b; ja = jb; }
        }
        if (c == 0) sIdx[r * 8 + ri] = ja;
    }
    __syncthreads();

    if (tid < MROWS) {
        out[1 + (size_t)N_TOK * DIM + rowBase + tid] = (float)sIdx[tid];
    }
    double lsum = 0.0;
    for (int row = 0; row < MROWS; ++row) {
        int idx = sIdx[row];
        float q  = emb[(size_t)idx * DIM + tid];
        float xv = xs[row][tid];
        out[1 + (size_t)(rowBase + row) * DIM + tid] = q;
        double df = (double)q - (double)xv;
        lsum += df * df;
    }
    #pragma unroll
    for (int off = 1; off < 64; off <<= 1) lsum += __shfl_xor(lsum, off, 64);
    __syncthreads();
    if ((tid & 63) == 0) sRed[tid >> 6] = lsum;
    __syncthreads();
    if (tid == 0) {
        atomicAdd(lossAcc, sRed[0] + sRed[1] + sRed[2] + sRed[3]);
    }
}

// ---------------------------------------------------------------------------
__global__ void finalize_kernel(const double* __restrict__ lossAcc, float* __restrict__ out) {
    out[0] = (float)(0.5 * (*lossAcc) / (double)((size_t)N_TOK * DIM));
}

extern "C" void kernel_launch(void* const* d_in, const int* in_sizes, int n_in,
                              void* d_out, int out_size, void* d_ws, size_t ws_size,
                              hipStream_t stream) {
    const float* x   = (const float*)d_in[0];   // [16,2048,256] fp32
    const float* emb = (const float*)d_in[1];   // [4096,256] fp32
    float* out = (float*)d_out;

    double* lossAcc = (double*)d_ws;
    float*  A       = (float*)((char*)d_ws + WS_A);
    float*  C       = (float*)((char*)d_ws + WS_C);
    unsigned short* e16 = (unsigned short*)((char*)d_ws + WS_E);

    const bool use_new = ws_size >= WS_NEED_NEW;

    hipMemsetAsync(d_ws, 0, 16, stream);
    xsq_np_kernel<<<N_TOK / 4, 256, 0, stream>>>(x, A);
    esq_np_kernel<<<KCB / 4, 256, 0, stream>>>(emb, C, use_new ? e16 : nullptr);
    if (use_new)
        vq_mfma<<<N_TOK / MROWS, 256, 0, stream>>>(x, emb, e16, A, C, out, lossAcc);
    else
        vq_np<<<N_TOK / MROWS, 256, 0, stream>>>(x, emb, A, C, out, lossAcc);
    finalize_kernel<<<1, 1, 0, stream>>>(lossAcc, out);
}

// Round 3
// 292.328 us; speedup vs baseline: 3.3527x; 1.2631x over previous
//
#include <hip/hip_runtime.h>

#define N_TOK 32768
#define DIM   256
#define KCB   4096
#define MROWS 64           // rows per block
#define XSP   260          // padded xstage row stride (floats)
#define NTILE (KCB / 16)   // 256 code-tiles of 16 codes
#define TILE_B 8448        // 16*256*2 (bf16, swizzled) + 256 (C floats, 64B valid)
// ---- legacy-kernel tile params (fallback path) ----
#define KT    256
#define NKT   (KCB / KT)
#define DC    8
#define NDC   (DIM / DC)
#define ESD   258

// ws layout (bytes):
//   0      : double lossAcc (zeroed by 16B memset)
//   16     : float A[N_TOK]  -- numpy-replica fp32 ||x_i||^2
//   131088 : float C[KCB]    -- fp32 ||e_k||^2
//   147472 : etiles[256][8448] -- pre-swizzled bf16 code-tiles + appended C
#define WS_A 16
#define WS_C (16 + 4 * N_TOK)
#define WS_E (WS_C + 4 * KCB)
#define WS_NEED_NEW ((size_t)WS_E + (size_t)NTILE * TILE_B)

#define CAP    28          // candidate list capacity per row
#define MARGIN 1.5e-3f     // > 2x worst-case bf16-approx error bound (~6.4e-4)

typedef __attribute__((ext_vector_type(8))) short short8v;  // 8 x bf16 bits
typedef __attribute__((ext_vector_type(4))) float f32x4;

__device__ __forceinline__ unsigned short f2bf_rne(float f) {
    unsigned u = __float_as_uint(f);
    unsigned r = (u + 0x7FFFu + ((u >> 16) & 1u)) >> 16;
    return (unsigned short)r;
}

// async global->LDS staging helpers (size must be literal)
__device__ __forceinline__ void gld16(const void* g, void* l) {
    __builtin_amdgcn_global_load_lds(
        (const __attribute__((address_space(1))) unsigned int*)g,
        (__attribute__((address_space(3))) unsigned int*)l, 16, 0, 0);
}
__device__ __forceinline__ void gld4(const void* g, void* l) {
    __builtin_amdgcn_global_load_lds(
        (const __attribute__((address_space(1))) unsigned int*)g,
        (__attribute__((address_space(3))) unsigned int*)l, 4, 0, 0);
}

// ---------------------------------------------------------------------------
// Kernel A: bit-exact replica of numpy's fp32 pairwise row sum-of-squares.
__global__ __launch_bounds__(256) void xsq_np_kernel(const float* __restrict__ x,
                                                     float* __restrict__ A) {
#pragma clang fp contract(off)
    __shared__ float xr[4][256];
    const int tid = threadIdx.x;
    const int w = tid >> 6, l = tid & 63;
    const int row = blockIdx.x * 4 + w;
    float4 v = *(const float4*)(x + (size_t)row * DIM + l * 4);
    xr[w][l * 4 + 0] = v.x; xr[w][l * 4 + 1] = v.y;
    xr[w][l * 4 + 2] = v.z; xr[w][l * 4 + 3] = v.w;
    __syncthreads();
    const float* t = xr[w];
    const int g = (l >> 4) & 1;
    const int j = l & 15;
    const int base = g * 128 + j;
    float t0 = t[base +   0] * t[base +   0];
    float t1 = t[base +  16] * t[base +  16];
    float t2 = t[base +  32] * t[base +  32];
    float t3 = t[base +  48] * t[base +  48];
    float t4 = t[base +  64] * t[base +  64];
    float t5 = t[base +  80] * t[base +  80];
    float t6 = t[base +  96] * t[base +  96];
    float t7 = t[base + 112] * t[base + 112];
    float p = ((t0 + t1) + (t2 + t3)) + ((t4 + t5) + (t6 + t7));
    p = p + __shfl_xor(p, 8, 64);
    p = p + __shfl_xor(p, 4, 64);
    p = p + __shfl_xor(p, 2, 64);
    p = p + __shfl_xor(p, 1, 64);
    float other = __shfl(p, 16, 64);
    if (l == 0) A[row] = p + other;
}

// ---------------------------------------------------------------------------
// Kernel B: C[k] exact; also emits PRE-SWIZZLED bf16 tiles + appended C when
// etiles != null. Swizzle: 16B unit u (= jj*32 + du) stored at u ^ (jj&7),
// so a linear global_load_lds copy + XOR'd ds_read is bank-conflict-free.
__global__ void esq_np_kernel(const float* __restrict__ emb, float* __restrict__ C,
                              unsigned char* __restrict__ etiles) {
#pragma clang fp contract(off)
    int row  = blockIdx.x * 4 + (threadIdx.x >> 6);
    int lane = threadIdx.x & 63;
    float4 v = *(const float4*)(emb + (size_t)row * DIM + lane * 4);
    int tile = row >> 4, jj = row & 15;
    if (etiles) {
        ushort4 h;
        h.x = f2bf_rne(v.x); h.y = f2bf_rne(v.y);
        h.z = f2bf_rne(v.z); h.w = f2bf_rne(v.w);
        int u  = jj * 32 + (lane >> 1);      // 16B unit within tile
        int qs = u ^ (jj & 7);               // swizzled unit
        *(ushort4*)(etiles + (size_t)tile * TILE_B + qs * 16 + (lane & 1) * 8) = h;
    }
    float s0 = v.x * v.x, s1 = v.y * v.y, s2 = v.z * v.z, s3 = v.w * v.w;
    double qd = (double)s0 + (double)s1 + (double)s2 + (double)s3;
    #pragma unroll
    for (int off = 32; off; off >>= 1) qd += __shfl_xor(qd, off, 64);
    if (lane == 0) {
        float cf = (float)qd;
        C[row] = cf;
        if (etiles)
            *(float*)(etiles + (size_t)tile * TILE_B + 8192 + jj * 4) = cf;
    }
}

// ---------------------------------------------------------------------------
// Exact fp32 score, bit-identical arithmetic to the proven-passing kernel.
__device__ __forceinline__ unsigned long long exact_pack(
    const float* __restrict__ emb, const float* __restrict__ C,
    const float* __restrict__ xsrow, float rowA, int k)
{
    const float4* er = (const float4*)(emb + (size_t)k * DIM);
    float acc = 0.f;
    #pragma unroll 8
    for (int d4 = 0; d4 < DIM / 4; ++d4) {
        float4 ev = er[d4];
        float4 xv = *(const float4*)(xsrow + d4 * 4);
        acc = fmaf(xv.x, ev.x, acc);
        acc = fmaf(xv.y, ev.y, acc);
        acc = fmaf(xv.z, ev.z, acc);
        acc = fmaf(xv.w, ev.w, acc);
    }
    float tmp = rowA - 2.0f * acc;
    float sc  = tmp + C[k];
    // scores strictly positive: bit pattern is monotone
    return ((unsigned long long)__float_as_uint(sc) << 32) | (unsigned)k;
}

// ---------------------------------------------------------------------------
// Kernel C: bf16-MFMA sweep. Per-wave private LDS double-buffer filled by
// async global_load_lds, counted vmcnt(9) (never 0), no barriers in sweep.
__global__ __launch_bounds__(256, 2) void vq_mfma(
    const float* __restrict__ x, const float* __restrict__ emb,
    const unsigned char* __restrict__ etiles,
    const float* __restrict__ A, const float* __restrict__ C,
    float* __restrict__ out, double* __restrict__ lossAcc)
{
    __shared__ union {
        float xstage[MROWS][XSP];                 // 66560 B (prologue only)
        unsigned char ebuf[4][2][TILE_B];         // 67584 B (sweep: per-wave dbuf)
    } sh;
    __shared__ int    cand[MROWS][CAP];           // 7168
    __shared__ int    cnt[MROWS];
    __shared__ float  waveMin[4][MROWS];
    __shared__ int    sIdx[MROWS];
    __shared__ double sRed[4];
    __shared__ unsigned long long bestA[4][MROWS];

    const int tid = threadIdx.x;
    const int w   = tid >> 6;        // wave 0..3 (owns code-tiles i*4+w)
    const int l   = tid & 63;
    const int jj  = l & 15;          // MFMA col lane (code within tile)
    const int g   = l >> 4;          // MFMA k-group / D row group
    const int rowBase = blockIdx.x * MROWS;

    // ---- stage x tile into (padded) LDS for the frag build ----
    #pragma unroll
    for (int p = 0; p < 16; ++p) {
        int flat = p * 256 + tid;
        int row = flat >> 6, d = (flat & 63) * 4;
        *(float4*)&sh.xstage[row][d] = *(const float4*)(x + (size_t)(rowBase + row) * DIM + d);
    }
    if (tid < MROWS) cnt[tid] = 0;
    __syncthreads();

    // ---- build all A fragments: 4 row-tiles x 8 k-steps (128 regs) ----
    short8v Af[4][8];
    #pragma unroll
    for (int t = 0; t < 4; ++t)
        #pragma unroll
        for (int s = 0; s < 8; ++s) {
            const float* xp = &sh.xstage[t * 16 + jj][s * 32 + g * 8];
            float4 a = *(const float4*)xp;
            float4 b = *(const float4*)(xp + 4);
            short8v f;
            f[0] = (short)f2bf_rne(a.x); f[1] = (short)f2bf_rne(a.y);
            f[2] = (short)f2bf_rne(a.z); f[3] = (short)f2bf_rne(a.w);
            f[4] = (short)f2bf_rne(b.x); f[5] = (short)f2bf_rne(b.y);
            f[6] = (short)f2bf_rne(b.z); f[7] = (short)f2bf_rne(b.w);
            Af[t][s] = f;
        }
    __syncthreads();   // all waves done reading xstage before ebuf overwrite

    // swizzled per-lane B-frag byte offsets (constant over tiles)
    const unsigned xorv = (unsigned)((jj & 7) << 4);
    int boff[8];
    #pragma unroll
    for (int s = 0; s < 8; ++s)
        boff[s] = (int)(((unsigned)(jj * 512 + s * 64 + g * 16)) ^ xorv);

    unsigned char* b0 = sh.ebuf[w][0];
    unsigned char* b1 = sh.ebuf[w][1];

    // STAGE: 9 async global->LDS ops for tile NT into BUF (wave-private)
#define STAGE(BUF, NT)                                                        \
    {                                                                         \
        const unsigned char* src_ = etiles + (size_t)(NT) * TILE_B;           \
        _Pragma("unroll")                                                     \
        for (int j_ = 0; j_ < 8; ++j_)                                        \
            gld16(src_ + j_ * 1024 + l * 16, (BUF) + j_ * 1024);              \
        gld4(src_ + 8192 + l * 4, (BUF) + 8192);                              \
    }

    // COMPUTE: 32 MFMA on BUF's tile + score handling (PHASE 0=min, 1=collect)
#define COMPUTE(BUF, NT, PHASE)                                               \
    {                                                                         \
        asm volatile("s_waitcnt vmcnt(9)" ::: "memory");                      \
        float Cv = *(const float*)((BUF) + 8192 + jj * 4);                    \
        f32x4 acc0 = {0,0,0,0}, acc1 = {0,0,0,0};                             \
        f32x4 acc2 = {0,0,0,0}, acc3 = {0,0,0,0};                             \
        __builtin_amdgcn_s_setprio(1);                                        \
        _Pragma("unroll")                                                     \
        for (int s_ = 0; s_ < 8; ++s_) {                                      \
            short8v B_ = *(const short8v*)((BUF) + boff[s_]);                 \
            acc0 = __builtin_amdgcn_mfma_f32_16x16x32_bf16(Af[0][s_], B_, acc0, 0, 0, 0); \
            acc1 = __builtin_amdgcn_mfma_f32_16x16x32_bf16(Af[1][s_], B_, acc1, 0, 0, 0); \
            acc2 = __builtin_amdgcn_mfma_f32_16x16x32_bf16(Af[2][s_], B_, acc2, 0, 0, 0); \
            acc3 = __builtin_amdgcn_mfma_f32_16x16x32_bf16(Af[3][s_], B_, acc3, 0, 0, 0); \
        }                                                                     \
        __builtin_amdgcn_s_setprio(0);                                        \
        _Pragma("unroll")                                                     \
        for (int r_ = 0; r_ < 4; ++r_) {                                      \
            float s0_ = fmaf(-2.f, acc0[r_], Cv);                             \
            float s1_ = fmaf(-2.f, acc1[r_], Cv);                             \
            float s2_ = fmaf(-2.f, acc2[r_], Cv);                             \
            float s3_ = fmaf(-2.f, acc3[r_], Cv);                             \
            if (PHASE == 0) {                                                 \
                mth[0][r_] = fminf(mth[0][r_], s0_);                          \
                mth[1][r_] = fminf(mth[1][r_], s1_);                          \
                mth[2][r_] = fminf(mth[2][r_], s2_);                          \
                mth[3][r_] = fminf(mth[3][r_], s3_);                          \
            } else {                                                          \
                int kc_ = (NT) * 16 + jj;                                     \
                if (s0_ <= mth[0][r_]) {                                      \
                    int row_ = 0 * 16 + g * 4 + r_;                           \
                    int p_ = atomicAdd(&cnt[row_], 1);                        \
                    if (p_ < CAP) cand[row_][p_] = kc_;                       \
                }                                                             \
                if (s1_ <= mth[1][r_]) {                                      \
                    int row_ = 1 * 16 + g * 4 + r_;                           \
                    int p_ = atomicAdd(&cnt[row_], 1);                        \
                    if (p_ < CAP) cand[row_][p_] = kc_;                       \
                }                                                             \
                if (s2_ <= mth[2][r_]) {                                      \
                    int row_ = 2 * 16 + g * 4 + r_;                           \
                    int p_ = atomicAdd(&cnt[row_], 1);                        \
                    if (p_ < CAP) cand[row_][p_] = kc_;                       \
                }                                                             \
                if (s3_ <= mth[3][r_]) {                                      \
                    int row_ = 3 * 16 + g * 4 + r_;                           \
                    int p_ = atomicAdd(&cnt[row_], 1);                        \
                    if (p_ < CAP) cand[row_][p_] = kc_;                       \
                }                                                             \
            }                                                                 \
        }                                                                     \
    }

    float mth[4][4];
    #pragma unroll
    for (int t = 0; t < 4; ++t)
        #pragma unroll
        for (int r = 0; r < 4; ++r) mth[t][r] = 3.4e38f;

    // ---- phase 0: approx min sweep (wave-private pipeline, no barriers) ----
    STAGE(b0, w);
    #pragma unroll 1
    for (int i = 0; i < 64; i += 2) {
        STAGE(b1, (i + 1) * 4 + w);
        COMPUTE(b0, i * 4 + w, 0);
        STAGE(b0, ((i + 2) & 63) * 4 + w);      // i=62 wraps: stages tile w for phase 1
        COMPUTE(b1, (i + 1) * 4 + w, 0);
    }

    // ---- reduce per-(t,r) mins across 16 code-lanes, then across waves ----
    #pragma unroll
    for (int t = 0; t < 4; ++t)
        #pragma unroll
        for (int r = 0; r < 4; ++r) {
            float v = mth[t][r];
            #pragma unroll
            for (int off = 1; off <= 8; off <<= 1)
                v = fminf(v, __shfl_xor(v, off, 16));
            mth[t][r] = v;
        }
    if (jj == 0) {
        #pragma unroll
        for (int t = 0; t < 4; ++t)
            #pragma unroll
            for (int r = 0; r < 4; ++r)
                waveMin[w][t * 16 + g * 4 + r] = mth[t][r];
    }
    __syncthreads();     // (drains vmcnt: b0's staged tile w is complete after this)
    if (tid < MROWS) {
        float m = fminf(fminf(waveMin[0][tid], waveMin[1][tid]),
                        fminf(waveMin[2][tid], waveMin[3][tid]));
        waveMin[0][tid] = m + MARGIN;            // per-row threshold
    }
    __syncthreads();
    #pragma unroll
    for (int t = 0; t < 4; ++t)
        #pragma unroll
        for (int r = 0; r < 4; ++r)
            mth[t][r] = waveMin[0][t * 16 + g * 4 + r];

    // ---- phase 1: collect candidates within margin (b0 pre-staged) ----
    #pragma unroll 1
    for (int i = 0; i < 64; i += 2) {
        STAGE(b1, (i + 1) * 4 + w);
        COMPUTE(b0, i * 4 + w, 1);
        STAGE(b0, ((i + 2) & 63) * 4 + w);
        COMPUTE(b1, (i + 1) * 4 + w, 1);
    }
    __syncthreads();     // drains dangling stages; cand/cnt visible to all

#undef STAGE
#undef COMPUTE

    // ---- exact fp32 rescore of candidates (4 threads per row) ----
    const int crow = tid & 63;
    const int sub  = tid >> 6;
    unsigned long long best = ~0ULL;
    {
        int cc = cnt[crow];
        float rowA = A[rowBase + crow];
        const float* xsrow = x + (size_t)(rowBase + crow) * DIM;
        if (cc <= CAP) {
            for (int c = sub; c < cc; c += 4) {
                unsigned long long pk = exact_pack(emb, C, xsrow, rowA, cand[crow][c]);
                best = best < pk ? best : pk;
            }
        } else {
            // overflow fallback (prob ~0): full exact scan of this row
            for (int k = sub; k < KCB; k += 4) {
                unsigned long long pk = exact_pack(emb, C, xsrow, rowA, k);
                best = best < pk ? best : pk;
            }
        }
    }
    bestA[sub][crow] = best;
    __syncthreads();
    if (tid < MROWS) {
        unsigned long long v0 = bestA[0][tid], v1 = bestA[1][tid];
        unsigned long long v2 = bestA[2][tid], v3 = bestA[3][tid];
        unsigned long long b = v0 < v1 ? v0 : v1;
        unsigned long long c2 = v2 < v3 ? v2 : v3;
        b = b < c2 ? b : c2;
        int idx = (int)(unsigned)(b & 0xFFFFFFFFull);
        sIdx[tid] = idx;
        out[1 + (size_t)N_TOK * DIM + rowBase + tid] = (float)idx;
    }
    __syncthreads();

    // ---- outputs: quantized gather (exact) + fp64 loss partial ----
    double lsum = 0.0;
    for (int row = 0; row < MROWS; ++row) {
        int idx = sIdx[row];
        float q  = emb[(size_t)idx * DIM + tid];
        float xv = x[(size_t)(rowBase + row) * DIM + tid];
        out[1 + (size_t)(rowBase + row) * DIM + tid] = q;
        double df = (double)q - (double)xv;
        lsum += df * df;
    }
    #pragma unroll
    for (int off = 1; off < 64; off <<= 1) lsum += __shfl_xor(lsum, off, 64);
    __syncthreads();
    if ((tid & 63) == 0) sRed[tid >> 6] = lsum;
    __syncthreads();
    if (tid == 0) atomicAdd(lossAcc, sRed[0] + sRed[1] + sRed[2] + sRed[3]);
}

// ---------------------------------------------------------------------------
// Legacy kernel (proven-passing), fallback if ws is too small.
__global__ __launch_bounds__(256, 2) void vq_np(
    const float* __restrict__ x, const float* __restrict__ emb,
    const float* __restrict__ A, const float* __restrict__ C,
    float* __restrict__ out, double* __restrict__ lossAcc)
{
    __shared__ float xs[MROWS][DIM];
    __shared__ float est[DC][ESD];
    __shared__ float sA[MROWS];
    __shared__ int   sIdx[MROWS];
    __shared__ double sRed[4];

    const int tid = threadIdx.x;
    const int c = tid & 31;
    const int r = tid >> 5;
    const int rowBase = blockIdx.x * MROWS;

    if (tid < MROWS) sA[tid] = A[rowBase + tid];

    #pragma unroll
    for (int p = 0; p < 16; ++p) {
        int flat = p * 256 + tid;
        int row = flat >> 6, d = (flat & 63) * 4;
        float4 v = *(const float4*)(x + (size_t)(rowBase + row) * DIM + d);
        *(float4*)&xs[row][d] = v;
    }

    float m1[8];
    int   i1[8];
    #pragma unroll
    for (int ri = 0; ri < 8; ++ri) { m1[ri] = 3.4e38f; i1[ri] = 0; }

    for (int kt = 0; kt < NKT; ++kt) {
        float acc[8][8];
        #pragma unroll
        for (int ri = 0; ri < 8; ++ri)
            #pragma unroll
            for (int kk = 0; kk < 8; ++kk) acc[ri][kk] = 0.f;

        for (int dc = 0; dc < NDC; ++dc) {
            const float* src = emb + (size_t)(kt * KT + tid) * DIM + dc * DC;
            float4 ea = *(const float4*)(src);
            float4 eb = *(const float4*)(src + 4);
            __syncthreads();
            est[0][tid] = ea.x; est[1][tid] = ea.y; est[2][tid] = ea.z; est[3][tid] = ea.w;
            est[4][tid] = eb.x; est[5][tid] = eb.y; est[6][tid] = eb.z; est[7][tid] = eb.w;
            __syncthreads();
            #pragma unroll
            for (int d4 = 0; d4 < 2; ++d4) {
                float4 xf[8];
                #pragma unroll
                for (int ri = 0; ri < 8; ++ri)
                    xf[ri] = *(const float4*)&xs[r * 8 + ri][dc * DC + d4 * 4];
                #pragma unroll
                for (int dd = 0; dd < 4; ++dd) {
                    float2 ev[4];
                    #pragma unroll
                    for (int j = 0; j < 4; ++j)
                        ev[j] = *(const float2*)&est[d4 * 4 + dd][2 * c + 64 * j];
                    #pragma unroll
                    for (int ri = 0; ri < 8; ++ri) {
                        float xv = (dd == 0) ? xf[ri].x : (dd == 1) ? xf[ri].y
                                 : (dd == 2) ? xf[ri].z : xf[ri].w;
                        #pragma unroll
                        for (int j = 0; j < 4; ++j) {
                            acc[ri][2 * j]     = fmaf(xv, ev[j].x, acc[ri][2 * j]);
                            acc[ri][2 * j + 1] = fmaf(xv, ev[j].y, acc[ri][2 * j + 1]);
                        }
                    }
                }
            }
        }
        #pragma unroll
        for (int j = 0; j < 4; ++j) {
            float2 Cv = *(const float2*)&C[kt * KT + 2 * c + 64 * j];
            #pragma unroll
            for (int p = 0; p < 2; ++p) {
                int kg = kt * KT + 2 * c + 64 * j + p;
                float Ck = (p == 0) ? Cv.x : Cv.y;
                #pragma unroll
                for (int ri = 0; ri < 8; ++ri) {
                    float tmp = sA[r * 8 + ri] - 2.0f * acc[ri][2 * j + p];
                    float s   = tmp + Ck;
                    if (s < m1[ri]) { m1[ri] = s; i1[ri] = kg; }
                }
            }
        }
    }

    #pragma unroll
    for (int ri = 0; ri < 8; ++ri) {
        float a = m1[ri]; int ja = i1[ri];
        #pragma unroll
        for (int off = 1; off <= 16; off <<= 1) {
            float b  = __shfl_xor(a, off, 64);
            int   jb = __shfl_xor(ja, off, 64);
            if (b < a || (b == a && jb < ja)) { a = b; ja = jb; }
        }
        if (c == 0) sIdx[r * 8 + ri] = ja;
    }
    __syncthreads();

    if (tid < MROWS) {
        out[1 + (size_t)N_TOK * DIM + rowBase + tid] = (float)sIdx[tid];
    }
    double lsum = 0.0;
    for (int row = 0; row < MROWS; ++row) {
        int idx = sIdx[row];
        float q  = emb[(size_t)idx * DIM + tid];
        float xv = xs[row][tid];
        out[1 + (size_t)(rowBase + row) * DIM + tid] = q;
        double df = (double)q - (double)xv;
        lsum += df * df;
    }
    #pragma unroll
    for (int off = 1; off < 64; off <<= 1) lsum += __shfl_xor(lsum, off, 64);
    __syncthreads();
    if ((tid & 63) == 0) sRed[tid >> 6] = lsum;
    __syncthreads();
    if (tid == 0) {
        atomicAdd(lossAcc, sRed[0] + sRed[1] + sRed[2] + sRed[3]);
    }
}

// ---------------------------------------------------------------------------
__global__ void finalize_kernel(const double* __restrict__ lossAcc, float* __restrict__ out) {
    out[0] = (float)(0.5 * (*lossAcc) / (double)((size_t)N_TOK * DIM));
}

extern "C" void kernel_launch(void* const* d_in, const int* in_sizes, int n_in,
                              void* d_out, int out_size, void* d_ws, size_t ws_size,
                              hipStream_t stream) {
    const float* x   = (const float*)d_in[0];   // [16,2048,256] fp32
    const float* emb = (const float*)d_in[1];   // [4096,256] fp32
    float* out = (float*)d_out;

    double* lossAcc = (double*)d_ws;
    float*  A       = (float*)((char*)d_ws + WS_A);
    float*  C       = (float*)((char*)d_ws + WS_C);
    unsigned char* etiles = (unsigned char*)((char*)d_ws + WS_E);

    const bool use_new = ws_size >= WS_NEED_NEW;

    hipMemsetAsync(d_ws, 0, 16, stream);
    xsq_np_kernel<<<N_TOK / 4, 256, 0, stream>>>(x, A);
    esq_np_kernel<<<KCB / 4, 256, 0, stream>>>(emb, C, use_new ? etiles : nullptr);
    if (use_new)
        vq_mfma<<<N_TOK / MROWS, 256, 0, stream>>>(x, emb, etiles, A, C, out, lossAcc);
    else
        vq_np<<<N_TOK / MROWS, 256, 0, stream>>>(x, emb, A, C, out, lossAcc);
    finalize_kernel<<<1, 1, 0, stream>>>(lossAcc, out);
}